// Round 6
// baseline (225.312 us; speedup 1.0000x reference)
//
// PointNet++ FP: three_nn + three_interpolate + pointwise MLP(384->256->128)
// Round 14: r10 structure (verified best: 110us fused, absmax 0.0156) +
// HIERARCHICAL group-min scan. r13 post-mortem: key-packing quantized the
// comparison (2^-11) -> selection flips -> 0.80 absmax. Selection must be
// bit-exact f32. This round keeps r10's exact compare semantics and cuts
// VALU by pruning:
//   Phase 1: all 256 cands, d via fmaf chain, reduce groups of 8 by pure
//            fmin tree (NO index/med3/cndmask): ~3.9 VALU/cand.
//   Phase 2: top-3 of the 32 group-mins WITH group index (32 x 11-op insert).
//   Phase 3: exact rescan of the 3 winning groups (24 cands, ascending
//            index, r10's full insert) -> identical d values/tie-breaks.
// Theorem: top-3 elements' groups have mins <= those elements; at most 2
// other groups have smaller mins -> top-3 \subseteq 3 smallest-min groups.
// Scan VALU/wave ~3584 -> ~1750 inst. Phase-3 adds 24 per-lane L2-hit loads
// (xyz2p XCD-local), hidden by TLP.
// Everything else r10 VERBATIM: 1024 blocks x 512 thr, wave=chunk lane=point
// s_load ping-pong, all-lane redundant fold, Xs[64][384] bf16 XOR-swizzled
// (48KB), 12-step L1, Y1 overlay, L2. 5 barriers.
// MFMA 16x16x32 bf16 layouts (learn_hip m89/m120 verified):
//   A: [m=lane&15][k=(lane>>4)*8+j]   B: [k=(lane>>4)*8+j][n=lane&15]
//   D: [row=(lane>>4)*4+reg][col=lane&15]
#include <hip/hip_runtime.h>

typedef __bf16 bf16_t;
typedef bf16_t bf16x2_t __attribute__((ext_vector_type(2)));
typedef bf16_t bf16x4_t __attribute__((ext_vector_type(4)));
typedef bf16_t bf16x8_t __attribute__((ext_vector_type(8)));
typedef float floatx4_t __attribute__((ext_vector_type(4)));

constexpr int B_ = 8, N_ = 8192, M_ = 2048;
constexpr int C1 = 128, C2 = 256;
constexpr int K1 = 384, N1 = 256, N2 = 128;

// ws layout (bytes)
constexpr size_t WS_W1T   = 0;         // bf16  [256][384]  = 196608 B
constexpr size_t WS_W2T   = 196608;    // bf16  [128][256]  =  65536 B
constexpr size_t WS_XYZ2P = 262144;    // float4[8*2048]    = 262144 B

// ---------------------------------------------------------------- prep ----
__global__ __launch_bounds__(256) void prep_kernel(
    const float* __restrict__ W1, const float* __restrict__ W2,
    const float* __restrict__ xyz2,
    bf16_t* __restrict__ W1T, bf16_t* __restrict__ W2T,
    float4* __restrict__ xyz2p) {
  int bid = blockIdx.x, tid = threadIdx.x;
  if (bid < 384) {                       // W1 [384][256] -> W1T [256][384]
    int t = bid * 256 + tid;             // 98304 elems
    int n = t / K1, k = t - n * K1;
    W1T[t] = (bf16_t)W1[k * N1 + n];
  } else if (bid < 512) {                // W2 [256][128] -> W2T [128][256]
    int t = (bid - 384) * 256 + tid;     // 32768 elems
    int n = t / N1, k = t - n * N1;
    W2T[t] = (bf16_t)W2[k * N2 + n];
  } else {                               // xyz2 -> float4{x,y,z,|q|^2}
    int t = (bid - 512) * 256 + tid;     // 16384 elems
    const float* p = xyz2 + (size_t)t * 3;
    float x = p[0], y = p[1], z = p[2];
    xyz2p[t] = make_float4(x, y, z, x * x + y * y + z * z);
  }
}

// ---------------------------------------------- fused nn+interp+MLP -------
// 1024 blocks x 512 threads; block owns 64 points of batch b = bi&7 (XCD-local
// points2/xyz2p in that XCD's L2). Wave w = candidate chunk of 256.
__global__ __launch_bounds__(512, 6) void fp_fused_kernel(
    const float* __restrict__ xyz1, const float4* __restrict__ xyz2p,
    const float* __restrict__ points1, const float* __restrict__ points2,
    const bf16_t* __restrict__ W1T, const float* __restrict__ b1,
    const bf16_t* __restrict__ W2T, const float* __restrict__ b2,
    float* __restrict__ out) {
  // Xs [64][384] bf16 swizzled (48KB); sd/si [8][64] float4/int4 overlay the
  // first 16KB during the scan; Y1 [64][256] bf16 overlays after layer 1.
  __shared__ __align__(16) char smem[64 * 768];   // 49152 B

  int bi = blockIdx.x;
  int b = bi & 7;                  // batch -> XCD (round-robin)
  int base = (bi >> 3) * 64;       // tile within batch (0..127)
  int tid = threadIdx.x;
  int wave = __builtin_amdgcn_readfirstlane(tid >> 6);  // 0..7
  int lane = tid & 63;
  size_t bN = (size_t)b * N_ + base;

  float4* sdv = (float4*)smem;             // [8][64] biased top-3 dists
  int4*   siv = (int4*)(smem + 8192);      // [8][64] top-3 indices

  float w0, w1, w2;                // blend weights (lane = point)
  int   i0, i1, i2;                // top-3 indices (lane = point)

  // ===== Phase S: three_nn, hierarchical. wave=chunk of 256, lane=point ===
  {
    const float* p1 = xyz1 + (bN + lane) * 3;
    float x = p1[0], y = p1[1], z = p1[2];
    float sq1 = x * x + y * y + z * z;
    float m2x = -2.0f * x, m2y = -2.0f * y, m2z = -2.0f * z;

    const float4* p2 = xyz2p + b * M_ + (wave << 8);  // wave-uniform base
    int jb = wave << 8;

    auto dist = [&](const float4& qv) {
      return fmaf(m2x, qv.x, fmaf(m2y, qv.y, fmaf(m2z, qv.z, qv.w)));
    };

    // ---- Phase 1: 32 group-mins (groups of 8), pure fmin tree ----
    float gm[32];
    float4 bA[8], bB[8];
#pragma unroll
    for (int t = 0; t < 8; ++t) bA[t] = p2[t];
#pragma unroll
    for (int j = 0; j < 256; j += 16) {
#pragma unroll
      for (int t = 0; t < 8; ++t) bB[t] = p2[j + 8 + t];
      {
        float d0 = dist(bA[0]), d1 = dist(bA[1]), d2 = dist(bA[2]), d3 = dist(bA[3]);
        float d4 = dist(bA[4]), d5 = dist(bA[5]), d6 = dist(bA[6]), d7 = dist(bA[7]);
        gm[j >> 3] = fminf(fminf(fminf(d0, d1), fminf(d2, d3)),
                           fminf(fminf(d4, d5), fminf(d6, d7)));
      }
      if (j + 16 < 256) {
#pragma unroll
        for (int t = 0; t < 8; ++t) bA[t] = p2[j + 16 + t];
      }
      {
        float d0 = dist(bB[0]), d1 = dist(bB[1]), d2 = dist(bB[2]), d3 = dist(bB[3]);
        float d4 = dist(bB[4]), d5 = dist(bB[5]), d6 = dist(bB[6]), d7 = dist(bB[7]);
        gm[(j >> 3) + 1] = fminf(fminf(fminf(d0, d1), fminf(d2, d3)),
                                 fminf(fminf(d4, d5), fminf(d6, d7)));
      }
    }

    // ---- Phase 2: top-3 group-mins with group index (ascending g) ----
    float t0 = 1e30f, t1 = 1e30f, t2 = 1e30f;
    int   g0 = 0, g1 = 0, g2 = 0;
#pragma unroll
    for (int g = 0; g < 32; ++g) {
      float d = gm[g];
      if (d < t2) {
        if (d < t1) {
          t2 = t1; g2 = g1;
          if (d < t0) { t1 = t0; g1 = g0; t0 = d; g0 = g; }
          else        { t1 = d;  g1 = g; }
        } else { t2 = d; g2 = g; }
      }
    }
    // sort winning groups ascending (tie-break = ref's ascending-index scan)
    int ga = min(g0, min(g1, g2));
    int gc = max(g0, max(g1, g2));
    int gb = g0 + g1 + g2 - ga - gc;

    // ---- Phase 3: exact rescan of the 3 winning groups (24 cands) ----
    float s0 = 1e30f, s1 = 1e30f, s2 = 1e30f;
    int   a0 = 0, a1 = 0, a2 = 0;
    auto procIdx = [&](const float4& qv, int jj) {
      float d = dist(qv);
      bool l0 = d < s0, l1 = d < s1, l2 = d < s2;
      float n0v = fminf(s0, d);
      float n1v = __builtin_amdgcn_fmed3f(d, s0, s1);
      float n2v = __builtin_amdgcn_fmed3f(d, s1, s2);
      int u1 = l0 ? a0 : jj;               // carry into slot1
      int u2 = l1 ? a1 : jj;               // carry into slot2
      a0 = l0 ? jj : a0;
      a1 = l1 ? u1 : a1;
      a2 = l2 ? u2 : a2;
      s0 = n0v; s1 = n1v; s2 = n2v;
    };
    auto scanGroup = [&](int gg) {
      const float4* pg = p2 + (gg << 3);
      float4 c[8];
#pragma unroll
      for (int t = 0; t < 8; ++t) c[t] = pg[t];
#pragma unroll
      for (int t = 0; t < 8; ++t) procIdx(c[t], jb + (gg << 3) + t);
    };
    scanGroup(ga); scanGroup(gb); scanGroup(gc);

    sdv[wave * 64 + lane] = make_float4(s0 + sq1, s1 + sq1, s2 + sq1, 0.0f);
    siv[wave * 64 + lane] = make_int4(a0, a1, a2, 0);
  }
  __syncthreads();

  // ===== Fold: every lane folds its point's 8 chunk-partials (redundant
  // across waves -> no serialization, results live in regs of lane=point). ===
  {
    float4 d0 = sdv[lane];  int4 x0 = siv[lane];
    float t0 = d0.x, t1 = d0.y, t2 = d0.z;
    int   a0 = x0.x, a1 = x0.y, a2 = x0.z;
    auto ins = [&](float d, int j) {
      if (d < t2) {
        if (d < t1) {
          t2 = t1; a2 = a1;
          if (d < t0) { t1 = t0; a1 = a0; t0 = d; a0 = j; }
          else        { t1 = d;  a1 = j; }
        } else { t2 = d; a2 = j; }
      }
    };
#pragma unroll
    for (int c = 1; c < 8; ++c) {
      float4 dd = sdv[c * 64 + lane];  int4 xx = siv[c * 64 + lane];
      ins(dd.x, xx.x); ins(dd.y, xx.y); ins(dd.z, xx.z);
    }
    float e0 = fmaxf(t0, 1e-10f), e1 = fmaxf(t1, 1e-10f), e2 = fmaxf(t2, 1e-10f);
    float r0 = 1.0f / e0, r1 = 1.0f / e1, r2 = 1.0f / e2;
    float rs = 1.0f / (r0 + r1 + r2);
    w0 = r0 * rs; w1 = r1 * rs; w2 = r2 * rs;
    i0 = a0; i1 = a1; i2 = a2;
  }
  __syncthreads();   // sd/si region about to be overwritten by Xs

  // ===== Phase A: gather -> Xs[64][384] bf16 swizzled ======================
  // wave w fills rows w*8..w*8+7 (interp cols 0..255 + skip cols 256..383).
#pragma unroll 2
  for (int i = 0; i < 8; ++i) {
    int p = wave * 8 + i;
    int j0 = __shfl(i0, p), j1 = __shfl(i1, p), j2 = __shfl(i2, p);
    float u0 = __shfl(w0, p), u1 = __shfl(w1, p), u2 = __shfl(w2, p);
    const float* g0 = points2 + ((size_t)b * M_ + j0) * C2 + lane * 4;
    const float* g1 = points2 + ((size_t)b * M_ + j1) * C2 + lane * 4;
    const float* g2 = points2 + ((size_t)b * M_ + j2) * C2 + lane * 4;
    float4 a0 = *(const float4*)g0;
    float4 a1 = *(const float4*)g1;
    float4 a2 = *(const float4*)g2;
    bf16x4_t v;
    v[0] = (bf16_t)(u0 * a0.x + u1 * a1.x + u2 * a2.x);
    v[1] = (bf16_t)(u0 * a0.y + u1 * a1.y + u2 * a2.y);
    v[2] = (bf16_t)(u0 * a0.z + u1 * a1.z + u2 * a2.z);
    v[3] = (bf16_t)(u0 * a0.w + u1 * a1.w + u2 * a2.w);
    int off = p * 768 + ((lane * 8) ^ (i << 4));      // (p&7)==i
    *(bf16x4_t*)(smem + off) = v;
    const float* pp1 = points1 + (bN + p) * C1 + lane * 2;
    float2 s = *(const float2*)pp1;
    bf16x2_t v2; v2[0] = (bf16_t)s.x; v2[1] = (bf16_t)s.y;
    int off2 = p * 768 + ((512 + lane * 4) ^ (i << 4));
    *(bf16x2_t*)(smem + off2) = v2;
  }
  __syncthreads();

  int q = lane >> 4, r = lane & 15;
  int rs8 = (r & 7) << 4;            // row-swizzle XOR (rows r,16+r,32+r,48+r)

  // ---- Layer 1: [64 x 384] x [384 x 256] -> Y1, wave owns 32 cols
  floatx4_t acc[4][2] = {};
  int cw = wave * 32;
  const bf16_t* wq0 = W1T + (size_t)(cw +      r) * K1;
  const bf16_t* wq1 = W1T + (size_t)(cw + 16 + r) * K1;
  for (int kk = 0; kk < 12; ++kk) {
    int k0 = kk * 32 + q * 8;
    int co = (k0 << 1) ^ rs8;
    bf16x8_t a0 = *(const bf16x8_t*)(smem + (     r) * 768 + co);
    bf16x8_t a1 = *(const bf16x8_t*)(smem + (16 + r) * 768 + co);
    bf16x8_t a2 = *(const bf16x8_t*)(smem + (32 + r) * 768 + co);
    bf16x8_t a3 = *(const bf16x8_t*)(smem + (48 + r) * 768 + co);
    bf16x8_t bb0 = *(const bf16x8_t*)(wq0 + k0);
    bf16x8_t bb1 = *(const bf16x8_t*)(wq1 + k0);
    acc[0][0] = __builtin_amdgcn_mfma_f32_16x16x32_bf16(a0, bb0, acc[0][0], 0, 0, 0);
    acc[1][0] = __builtin_amdgcn_mfma_f32_16x16x32_bf16(a1, bb0, acc[1][0], 0, 0, 0);
    acc[2][0] = __builtin_amdgcn_mfma_f32_16x16x32_bf16(a2, bb0, acc[2][0], 0, 0, 0);
    acc[3][0] = __builtin_amdgcn_mfma_f32_16x16x32_bf16(a3, bb0, acc[3][0], 0, 0, 0);
    acc[0][1] = __builtin_amdgcn_mfma_f32_16x16x32_bf16(a0, bb1, acc[0][1], 0, 0, 0);
    acc[1][1] = __builtin_amdgcn_mfma_f32_16x16x32_bf16(a1, bb1, acc[1][1], 0, 0, 0);
    acc[2][1] = __builtin_amdgcn_mfma_f32_16x16x32_bf16(a2, bb1, acc[2][1], 0, 0, 0);
    acc[3][1] = __builtin_amdgcn_mfma_f32_16x16x32_bf16(a3, bb1, acc[3][1], 0, 0, 0);
  }
  __syncthreads();   // Xs dead only when ALL waves finished layer-1 LDS reads

  // bias + relu -> Y1 [64][256] bf16 (overlays Xs, 512B rows, same swizzle)
#pragma unroll
  for (int ct = 0; ct < 2; ++ct) {
    int nn = cw + ct * 16 + r;
    float bias = b1[nn];
#pragma unroll
    for (int mt = 0; mt < 4; ++mt) {
#pragma unroll
      for (int reg = 0; reg < 4; ++reg) {
        int m = mt * 16 + q * 4 + reg;
        int off = (m << 9) + ((nn << 1) ^ ((m & 7) << 4));
        *(bf16_t*)(smem + off) = (bf16_t)fmaxf(acc[mt][ct][reg] + bias, 0.0f);
      }
    }
  }
  __syncthreads();

  // ---- Layer 2: [64 x 256] x [256 x 128] -> out, wave owns 16 cols
  floatx4_t acc2[4] = {};
  const bf16_t* vq = W2T + (size_t)(wave * 16 + r) * N1;
  for (int kk = 0; kk < 8; ++kk) {
    int k0 = kk * 32 + q * 8;
    int co = (k0 << 1) ^ rs8;
    bf16x8_t a0 = *(const bf16x8_t*)(smem + ((     r) << 9) + co);
    bf16x8_t a1 = *(const bf16x8_t*)(smem + ((16 + r) << 9) + co);
    bf16x8_t a2 = *(const bf16x8_t*)(smem + ((32 + r) << 9) + co);
    bf16x8_t a3 = *(const bf16x8_t*)(smem + ((48 + r) << 9) + co);
    bf16x8_t bb = *(const bf16x8_t*)(vq + k0);
    acc2[0] = __builtin_amdgcn_mfma_f32_16x16x32_bf16(a0, bb, acc2[0], 0, 0, 0);
    acc2[1] = __builtin_amdgcn_mfma_f32_16x16x32_bf16(a1, bb, acc2[1], 0, 0, 0);
    acc2[2] = __builtin_amdgcn_mfma_f32_16x16x32_bf16(a2, bb, acc2[2], 0, 0, 0);
    acc2[3] = __builtin_amdgcn_mfma_f32_16x16x32_bf16(a3, bb, acc2[3], 0, 0, 0);
  }
  {
    int cc = wave * 16 + r;
    float bias = b2[cc];
#pragma unroll
    for (int mt = 0; mt < 4; ++mt) {
#pragma unroll
      for (int reg = 0; reg < 4; ++reg) {
        int m = mt * 16 + q * 4 + reg;
        out[(bN + m) * N2 + cc] = fmaxf(acc2[mt][reg] + bias, 0.0f);
      }
    }
  }
}

// ----------------------------------------------------------------- launch --
extern "C" void kernel_launch(void* const* d_in, const int* in_sizes, int n_in,
                              void* d_out, int out_size, void* d_ws, size_t ws_size,
                              hipStream_t stream) {
  (void)in_sizes; (void)n_in; (void)out_size; (void)ws_size;
  const float* xyz1    = (const float*)d_in[0];
  const float* xyz2    = (const float*)d_in[1];
  const float* points1 = (const float*)d_in[2];
  const float* points2 = (const float*)d_in[3];
  const float* W1      = (const float*)d_in[4];
  const float* b1      = (const float*)d_in[5];
  const float* W2      = (const float*)d_in[6];
  const float* b2      = (const float*)d_in[7];
  float* out = (float*)d_out;
  char* ws = (char*)d_ws;
  bf16_t* W1T   = (bf16_t*)(ws + WS_W1T);
  bf16_t* W2T   = (bf16_t*)(ws + WS_W2T);
  float4* xyz2p = (float4*)(ws + WS_XYZ2P);

  prep_kernel<<<576, 256, 0, stream>>>(W1, W2, xyz2, W1T, W2T, xyz2p);
  fp_fused_kernel<<<1024, 512, 0, stream>>>(xyz1, xyz2p, points1, points2,
                                            W1T, b1, W2T, b2, out);
}

// Round 8
// 202.003 us; speedup vs baseline: 1.1154x; 1.1154x over previous
//
// PointNet++ FP: three_nn + three_interpolate + pointwise MLP(384->256->128)
// Round 16 = r15 resubmitted verbatim (r15 bench was an infra failure:
// "MI355X container failed twice" -- no signal on the kernel itself).
// r15 design: r10 structure + ONLINE hierarchical scan (no arrays).
// r14 post-mortem: gm[32] array -> 60MB scratch spills (WRITE 40->95MB),
// fused 137us. The pruning theorem itself passed correctness. This round
// keeps it but REGISTER-FLAT:
//   Phase 1+2 fused: per 8-cand batch, d's (8 transient regs) -> fmin/min3
//     tree -> ONE branchless 11-op insert of (gmin, gid) into 6 regs.
//   Phase 3: rescan the 3 winning groups (24 cands) with r10's exact
//     index-tracking insert; loads bounded to 4 float4 transients via
//     unroll-1 halves; three EXPLICIT scanGroup calls (no gs[] array,
//     rule #20) so nothing hoists or goes to scratch.
// Superset theorem (verified by r14's pass): top-3 elements live in the 3
// groups with smallest mins; strict < keeps earlier group on ties; rescan
// ascending (ga<gb<gc sorted) reproduces reference tie-breaks exactly.
// Scan VALU/wave ~3600 -> ~1700. Phase-3 loads are XCD-L2/L1-hot (xyz2p is
// 32KB/batch, just streamed in phase 1).
// SPILL TRIPWIRE: WRITE_SIZE must stay ~40MB; >50MB = scratch -> revert.
// Everything else r10 VERBATIM: 1024 blocks x 512 thr, wave=chunk lane=point
// s_load ping-pong, all-lane redundant fold, Xs[64][384] bf16 XOR-swizzled
// (48KB), 12-step L1, Y1 overlay, L2. 5 barriers.
// MFMA 16x16x32 bf16 layouts (learn_hip m89/m120 verified):
//   A: [m=lane&15][k=(lane>>4)*8+j]   B: [k=(lane>>4)*8+j][n=lane&15]
//   D: [row=(lane>>4)*4+reg][col=lane&15]
#include <hip/hip_runtime.h>

typedef __bf16 bf16_t;
typedef bf16_t bf16x2_t __attribute__((ext_vector_type(2)));
typedef bf16_t bf16x4_t __attribute__((ext_vector_type(4)));
typedef bf16_t bf16x8_t __attribute__((ext_vector_type(8)));
typedef float floatx4_t __attribute__((ext_vector_type(4)));

constexpr int B_ = 8, N_ = 8192, M_ = 2048;
constexpr int C1 = 128, C2 = 256;
constexpr int K1 = 384, N1 = 256, N2 = 128;

// ws layout (bytes)
constexpr size_t WS_W1T   = 0;         // bf16  [256][384]  = 196608 B
constexpr size_t WS_W2T   = 196608;    // bf16  [128][256]  =  65536 B
constexpr size_t WS_XYZ2P = 262144;    // float4[8*2048]    = 262144 B

// ---------------------------------------------------------------- prep ----
__global__ __launch_bounds__(256) void prep_kernel(
    const float* __restrict__ W1, const float* __restrict__ W2,
    const float* __restrict__ xyz2,
    bf16_t* __restrict__ W1T, bf16_t* __restrict__ W2T,
    float4* __restrict__ xyz2p) {
  int bid = blockIdx.x, tid = threadIdx.x;
  if (bid < 384) {                       // W1 [384][256] -> W1T [256][384]
    int t = bid * 256 + tid;             // 98304 elems
    int n = t / K1, k = t - n * K1;
    W1T[t] = (bf16_t)W1[k * N1 + n];
  } else if (bid < 512) {                // W2 [256][128] -> W2T [128][256]
    int t = (bid - 384) * 256 + tid;     // 32768 elems
    int n = t / N1, k = t - n * N1;
    W2T[t] = (bf16_t)W2[k * N2 + n];
  } else {                               // xyz2 -> float4{x,y,z,|q|^2}
    int t = (bid - 512) * 256 + tid;     // 16384 elems
    const float* p = xyz2 + (size_t)t * 3;
    float x = p[0], y = p[1], z = p[2];
    xyz2p[t] = make_float4(x, y, z, x * x + y * y + z * z);
  }
}

// ---------------------------------------------- fused nn+interp+MLP -------
// 1024 blocks x 512 threads; block owns 64 points of batch b = bi&7 (XCD-local
// points2/xyz2p in that XCD's L2). Wave w = candidate chunk of 256.
__global__ __launch_bounds__(512, 6) void fp_fused_kernel(
    const float* __restrict__ xyz1, const float4* __restrict__ xyz2p,
    const float* __restrict__ points1, const float* __restrict__ points2,
    const bf16_t* __restrict__ W1T, const float* __restrict__ b1,
    const bf16_t* __restrict__ W2T, const float* __restrict__ b2,
    float* __restrict__ out) {
  // Xs [64][384] bf16 swizzled (48KB); sd/si [8][64] float4/int4 overlay the
  // first 16KB during the scan; Y1 [64][256] bf16 overlays after layer 1.
  __shared__ __align__(16) char smem[64 * 768];   // 49152 B

  int bi = blockIdx.x;
  int b = bi & 7;                  // batch -> XCD (round-robin)
  int base = (bi >> 3) * 64;       // tile within batch (0..127)
  int tid = threadIdx.x;
  int wave = __builtin_amdgcn_readfirstlane(tid >> 6);  // 0..7
  int lane = tid & 63;
  size_t bN = (size_t)b * N_ + base;

  float4* sdv = (float4*)smem;             // [8][64] biased top-3 dists
  int4*   siv = (int4*)(smem + 8192);      // [8][64] top-3 indices

  float w0, w1, w2;                // blend weights (lane = point)
  int   i0, i1, i2;                // top-3 indices (lane = point)

  // ===== Phase S: three_nn, online-hierarchical. wave=chunk, lane=point ===
  {
    const float* p1 = xyz1 + (bN + lane) * 3;
    float x = p1[0], y = p1[1], z = p1[2];
    float sq1 = x * x + y * y + z * z;
    float m2x = -2.0f * x, m2y = -2.0f * y, m2z = -2.0f * z;

    const float4* p2 = xyz2p + b * M_ + (wave << 8);  // wave-uniform base
    int jb = wave << 8;

    auto dist = [&](const float4& qv) {
      return fmaf(m2x, qv.x, fmaf(m2y, qv.y, fmaf(m2z, qv.z, qv.w)));
    };

    // top-3 group-mins (6 regs, no arrays)
    float t0 = 1e30f, t1 = 1e30f, t2 = 1e30f;
    int   g0 = 0, g1 = 0, g2 = 0;
    auto insG = [&](float d, int g) {       // branchless, strict <
      bool l0 = d < t0, l1 = d < t1, l2 = d < t2;
      float n0 = fminf(t0, d);
      float n1 = __builtin_amdgcn_fmed3f(d, t0, t1);
      float n2 = __builtin_amdgcn_fmed3f(d, t1, t2);
      int u1 = l0 ? g0 : g;
      int u2 = l1 ? g1 : g;
      g0 = l0 ? g : g0;
      g1 = l1 ? u1 : g1;
      g2 = l2 ? u2 : g2;
      t0 = n0; t1 = n1; t2 = n2;
    };
    auto gmin8 = [&](const float4* c) {     // fmin tree (fuses to v_min3)
      float d0 = dist(c[0]), d1 = dist(c[1]), d2 = dist(c[2]), d3 = dist(c[3]);
      float d4 = dist(c[4]), d5 = dist(c[5]), d6 = dist(c[6]), d7 = dist(c[7]);
      return fminf(fminf(fminf(d0, d1), fminf(d2, d3)),
                   fminf(fminf(d4, d5), fminf(d6, d7)));
    };

    float4 bA[8], bB[8];
#pragma unroll
    for (int t = 0; t < 8; ++t) bA[t] = p2[t];
#pragma unroll
    for (int j = 0; j < 256; j += 16) {
#pragma unroll
      for (int t = 0; t < 8; ++t) bB[t] = p2[j + 8 + t];
      insG(gmin8(bA), j >> 3);
      if (j + 16 < 256) {
#pragma unroll
        for (int t = 0; t < 8; ++t) bA[t] = p2[j + 16 + t];
      }
      insG(gmin8(bB), (j >> 3) + 1);
    }

    // sort winning groups ascending (ref tie-break = ascending-index scan)
    int ga = min(g0, min(g1, g2));
    int gc = max(g0, max(g1, g2));
    int gb = g0 + g1 + g2 - ga - gc;

    // ---- Phase 3: exact rescan of the 3 winning groups (24 cands) ----
    float s0 = 1e30f, s1 = 1e30f, s2 = 1e30f;
    int   a0 = 0, a1 = 0, a2 = 0;
    auto procIdx = [&](const float4& qv, int jj) {
      float d = dist(qv);
      bool l0 = d < s0, l1 = d < s1, l2 = d < s2;
      float n0v = fminf(s0, d);
      float n1v = __builtin_amdgcn_fmed3f(d, s0, s1);
      float n2v = __builtin_amdgcn_fmed3f(d, s1, s2);
      int u1 = l0 ? a0 : jj;               // carry into slot1
      int u2 = l1 ? a1 : jj;               // carry into slot2
      a0 = l0 ? jj : a0;
      a1 = l1 ? u1 : a1;
      a2 = l2 ? u2 : a2;
      s0 = n0v; s1 = n1v; s2 = n2v;
    };
    auto scanGroup = [&](int gg) {
      const float4* pg = p2 + (gg << 3);   // per-lane address (vector loads)
      int jg = jb + (gg << 3);
#pragma unroll 1
      for (int h = 0; h < 2; ++h) {        // 4 float4 transients max
        float4 c0 = pg[h * 4 + 0], c1 = pg[h * 4 + 1];
        float4 c2 = pg[h * 4 + 2], c3 = pg[h * 4 + 3];
        procIdx(c0, jg + h * 4 + 0);
        procIdx(c1, jg + h * 4 + 1);
        procIdx(c2, jg + h * 4 + 2);
        procIdx(c3, jg + h * 4 + 3);
      }
    };
    scanGroup(ga); scanGroup(gb); scanGroup(gc);

    sdv[wave * 64 + lane] = make_float4(s0 + sq1, s1 + sq1, s2 + sq1, 0.0f);
    siv[wave * 64 + lane] = make_int4(a0, a1, a2, 0);
  }
  __syncthreads();

  // ===== Fold: every lane folds its point's 8 chunk-partials (redundant
  // across waves -> no serialization, results live in regs of lane=point). ===
  {
    float4 d0 = sdv[lane];  int4 x0 = siv[lane];
    float t0 = d0.x, t1 = d0.y, t2 = d0.z;
    int   a0 = x0.x, a1 = x0.y, a2 = x0.z;
    auto ins = [&](float d, int j) {
      if (d < t2) {
        if (d < t1) {
          t2 = t1; a2 = a1;
          if (d < t0) { t1 = t0; a1 = a0; t0 = d; a0 = j; }
          else        { t1 = d;  a1 = j; }
        } else { t2 = d; a2 = j; }
      }
    };
#pragma unroll
    for (int c = 1; c < 8; ++c) {
      float4 dd = sdv[c * 64 + lane];  int4 xx = siv[c * 64 + lane];
      ins(dd.x, xx.x); ins(dd.y, xx.y); ins(dd.z, xx.z);
    }
    float e0 = fmaxf(t0, 1e-10f), e1 = fmaxf(t1, 1e-10f), e2 = fmaxf(t2, 1e-10f);
    float r0 = 1.0f / e0, r1 = 1.0f / e1, r2 = 1.0f / e2;
    float rs = 1.0f / (r0 + r1 + r2);
    w0 = r0 * rs; w1 = r1 * rs; w2 = r2 * rs;
    i0 = a0; i1 = a1; i2 = a2;
  }
  __syncthreads();   // sd/si region about to be overwritten by Xs

  // ===== Phase A: gather -> Xs[64][384] bf16 swizzled ======================
  // wave w fills rows w*8..w*8+7 (interp cols 0..255 + skip cols 256..383).
#pragma unroll 2
  for (int i = 0; i < 8; ++i) {
    int p = wave * 8 + i;
    int j0 = __shfl(i0, p), j1 = __shfl(i1, p), j2 = __shfl(i2, p);
    float u0 = __shfl(w0, p), u1 = __shfl(w1, p), u2 = __shfl(w2, p);
    const float* g0 = points2 + ((size_t)b * M_ + j0) * C2 + lane * 4;
    const float* g1 = points2 + ((size_t)b * M_ + j1) * C2 + lane * 4;
    const float* g2 = points2 + ((size_t)b * M_ + j2) * C2 + lane * 4;
    float4 a0 = *(const float4*)g0;
    float4 a1 = *(const float4*)g1;
    float4 a2 = *(const float4*)g2;
    bf16x4_t v;
    v[0] = (bf16_t)(u0 * a0.x + u1 * a1.x + u2 * a2.x);
    v[1] = (bf16_t)(u0 * a0.y + u1 * a1.y + u2 * a2.y);
    v[2] = (bf16_t)(u0 * a0.z + u1 * a1.z + u2 * a2.z);
    v[3] = (bf16_t)(u0 * a0.w + u1 * a1.w + u2 * a2.w);
    int off = p * 768 + ((lane * 8) ^ (i << 4));      // (p&7)==i
    *(bf16x4_t*)(smem + off) = v;
    const float* pp1 = points1 + (bN + p) * C1 + lane * 2;
    float2 s = *(const float2*)pp1;
    bf16x2_t v2; v2[0] = (bf16_t)s.x; v2[1] = (bf16_t)s.y;
    int off2 = p * 768 + ((512 + lane * 4) ^ (i << 4));
    *(bf16x2_t*)(smem + off2) = v2;
  }
  __syncthreads();

  int q = lane >> 4, r = lane & 15;
  int rs8 = (r & 7) << 4;            // row-swizzle XOR (rows r,16+r,32+r,48+r)

  // ---- Layer 1: [64 x 384] x [384 x 256] -> Y1, wave owns 32 cols
  floatx4_t acc[4][2] = {};
  int cw = wave * 32;
  const bf16_t* wq0 = W1T + (size_t)(cw +      r) * K1;
  const bf16_t* wq1 = W1T + (size_t)(cw + 16 + r) * K1;
  for (int kk = 0; kk < 12; ++kk) {
    int k0 = kk * 32 + q * 8;
    int co = (k0 << 1) ^ rs8;
    bf16x8_t a0 = *(const bf16x8_t*)(smem + (     r) * 768 + co);
    bf16x8_t a1 = *(const bf16x8_t*)(smem + (16 + r) * 768 + co);
    bf16x8_t a2 = *(const bf16x8_t*)(smem + (32 + r) * 768 + co);
    bf16x8_t a3 = *(const bf16x8_t*)(smem + (48 + r) * 768 + co);
    bf16x8_t bb0 = *(const bf16x8_t*)(wq0 + k0);
    bf16x8_t bb1 = *(const bf16x8_t*)(wq1 + k0);
    acc[0][0] = __builtin_amdgcn_mfma_f32_16x16x32_bf16(a0, bb0, acc[0][0], 0, 0, 0);
    acc[1][0] = __builtin_amdgcn_mfma_f32_16x16x32_bf16(a1, bb0, acc[1][0], 0, 0, 0);
    acc[2][0] = __builtin_amdgcn_mfma_f32_16x16x32_bf16(a2, bb0, acc[2][0], 0, 0, 0);
    acc[3][0] = __builtin_amdgcn_mfma_f32_16x16x32_bf16(a3, bb0, acc[3][0], 0, 0, 0);
    acc[0][1] = __builtin_amdgcn_mfma_f32_16x16x32_bf16(a0, bb1, acc[0][1], 0, 0, 0);
    acc[1][1] = __builtin_amdgcn_mfma_f32_16x16x32_bf16(a1, bb1, acc[1][1], 0, 0, 0);
    acc[2][1] = __builtin_amdgcn_mfma_f32_16x16x32_bf16(a2, bb1, acc[2][1], 0, 0, 0);
    acc[3][1] = __builtin_amdgcn_mfma_f32_16x16x32_bf16(a3, bb1, acc[3][1], 0, 0, 0);
  }
  __syncthreads();   // Xs dead only when ALL waves finished layer-1 LDS reads

  // bias + relu -> Y1 [64][256] bf16 (overlays Xs, 512B rows, same swizzle)
#pragma unroll
  for (int ct = 0; ct < 2; ++ct) {
    int nn = cw + ct * 16 + r;
    float bias = b1[nn];
#pragma unroll
    for (int mt = 0; mt < 4; ++mt) {
#pragma unroll
      for (int reg = 0; reg < 4; ++reg) {
        int m = mt * 16 + q * 4 + reg;
        int off = (m << 9) + ((nn << 1) ^ ((m & 7) << 4));
        *(bf16_t*)(smem + off) = (bf16_t)fmaxf(acc[mt][ct][reg] + bias, 0.0f);
      }
    }
  }
  __syncthreads();

  // ---- Layer 2: [64 x 256] x [256 x 128] -> out, wave owns 16 cols
  floatx4_t acc2[4] = {};
  const bf16_t* vq = W2T + (size_t)(wave * 16 + r) * N1;
  for (int kk = 0; kk < 8; ++kk) {
    int k0 = kk * 32 + q * 8;
    int co = (k0 << 1) ^ rs8;
    bf16x8_t a0 = *(const bf16x8_t*)(smem + ((     r) << 9) + co);
    bf16x8_t a1 = *(const bf16x8_t*)(smem + ((16 + r) << 9) + co);
    bf16x8_t a2 = *(const bf16x8_t*)(smem + ((32 + r) << 9) + co);
    bf16x8_t a3 = *(const bf16x8_t*)(smem + ((48 + r) << 9) + co);
    bf16x8_t bb = *(const bf16x8_t*)(vq + k0);
    acc2[0] = __builtin_amdgcn_mfma_f32_16x16x32_bf16(a0, bb, acc2[0], 0, 0, 0);
    acc2[1] = __builtin_amdgcn_mfma_f32_16x16x32_bf16(a1, bb, acc2[1], 0, 0, 0);
    acc2[2] = __builtin_amdgcn_mfma_f32_16x16x32_bf16(a2, bb, acc2[2], 0, 0, 0);
    acc2[3] = __builtin_amdgcn_mfma_f32_16x16x32_bf16(a3, bb, acc2[3], 0, 0, 0);
  }
  {
    int cc = wave * 16 + r;
    float bias = b2[cc];
#pragma unroll
    for (int mt = 0; mt < 4; ++mt) {
#pragma unroll
      for (int reg = 0; reg < 4; ++reg) {
        int m = mt * 16 + q * 4 + reg;
        out[(bN + m) * N2 + cc] = fmaxf(acc2[mt][reg] + bias, 0.0f);
      }
    }
  }
}

// ----------------------------------------------------------------- launch --
extern "C" void kernel_launch(void* const* d_in, const int* in_sizes, int n_in,
                              void* d_out, int out_size, void* d_ws, size_t ws_size,
                              hipStream_t stream) {
  (void)in_sizes; (void)n_in; (void)out_size; (void)ws_size;
  const float* xyz1    = (const float*)d_in[0];
  const float* xyz2    = (const float*)d_in[1];
  const float* points1 = (const float*)d_in[2];
  const float* points2 = (const float*)d_in[3];
  const float* W1      = (const float*)d_in[4];
  const float* b1      = (const float*)d_in[5];
  const float* W2      = (const float*)d_in[6];
  const float* b2      = (const float*)d_in[7];
  float* out = (float*)d_out;
  char* ws = (char*)d_ws;
  bf16_t* W1T   = (bf16_t*)(ws + WS_W1T);
  bf16_t* W2T   = (bf16_t*)(ws + WS_W2T);
  float4* xyz2p = (float4*)(ws + WS_XYZ2P);

  prep_kernel<<<576, 256, 0, stream>>>(W1, W2, xyz2, W1T, W2T, xyz2p);
  fp_fused_kernel<<<1024, 512, 0, stream>>>(xyz1, xyz2p, points1, points2,
                                            W1T, b1, W2T, b2, out);
}

// Round 9
// 176.436 us; speedup vs baseline: 1.2770x; 1.1449x over previous
//
// PointNet++ FP: three_nn + three_interpolate + pointwise MLP(384->256->128)
// Round 17: r16 + LDS-fed scan. r16 counters: VALUBusy 66->33% with flat
// wall (117us) after halving scan VALU -> scan is now LOAD-latency-bound on
// the scalar path (s_load ping-pong 1 batch deep; 24 waves/CU thrash the
// small shared scalar cache). Whole-scan VALU floor is only ~10us chip-wide.
// Fix: stage xyz2p[b] (2048 float4 = 32KB) into LDS once per block
// (coalesced, 64B/thread) -- exactly the free LDS during the scan (sd/si
// 16KB + stage 32KB = 48KB = Xs region, dead until gather). Scan reads
// become ds_read_b128 same-address broadcasts (conflict-free, m136), deep
// lgkmcnt queue + 6 waves/SIMD TLP hides the ~120cyc latency. Phase-3
// rescan also from LDS (per-lane divergent, 24 one-off reads).
// Arithmetic BIT-IDENTICAL to r16 (passed): same f32 values, same insert
// order, same tie-breaks. One extra barrier (stage->scan).
// SPILL TRIPWIRE: WRITE_SIZE must stay ~42MB; >50MB = scratch -> revert.
// Online-hierarchical scan (r15/r16): per 8-cand group, fmin tree -> one
// branchless (gmin,gid) insert into 6 regs; then exact rescan of the 3
// winning groups (superset theorem, verified r14/r16).
// Everything else r10 VERBATIM: 1024 blocks x 512 thr, all-lane redundant
// fold, Xs[64][384] bf16 XOR-swizzled (48KB), 12-step L1, Y1 overlay, L2.
// MFMA 16x16x32 bf16 layouts (learn_hip m89/m120 verified):
//   A: [m=lane&15][k=(lane>>4)*8+j]   B: [k=(lane>>4)*8+j][n=lane&15]
//   D: [row=(lane>>4)*4+reg][col=lane&15]
#include <hip/hip_runtime.h>

typedef __bf16 bf16_t;
typedef bf16_t bf16x2_t __attribute__((ext_vector_type(2)));
typedef bf16_t bf16x4_t __attribute__((ext_vector_type(4)));
typedef bf16_t bf16x8_t __attribute__((ext_vector_type(8)));
typedef float floatx4_t __attribute__((ext_vector_type(4)));

constexpr int B_ = 8, N_ = 8192, M_ = 2048;
constexpr int C1 = 128, C2 = 256;
constexpr int K1 = 384, N1 = 256, N2 = 128;

// ws layout (bytes)
constexpr size_t WS_W1T   = 0;         // bf16  [256][384]  = 196608 B
constexpr size_t WS_W2T   = 196608;    // bf16  [128][256]  =  65536 B
constexpr size_t WS_XYZ2P = 262144;    // float4[8*2048]    = 262144 B

// ---------------------------------------------------------------- prep ----
__global__ __launch_bounds__(256) void prep_kernel(
    const float* __restrict__ W1, const float* __restrict__ W2,
    const float* __restrict__ xyz2,
    bf16_t* __restrict__ W1T, bf16_t* __restrict__ W2T,
    float4* __restrict__ xyz2p) {
  int bid = blockIdx.x, tid = threadIdx.x;
  if (bid < 384) {                       // W1 [384][256] -> W1T [256][384]
    int t = bid * 256 + tid;             // 98304 elems
    int n = t / K1, k = t - n * K1;
    W1T[t] = (bf16_t)W1[k * N1 + n];
  } else if (bid < 512) {                // W2 [256][128] -> W2T [128][256]
    int t = (bid - 384) * 256 + tid;     // 32768 elems
    int n = t / N1, k = t - n * N1;
    W2T[t] = (bf16_t)W2[k * N2 + n];
  } else {                               // xyz2 -> float4{x,y,z,|q|^2}
    int t = (bid - 512) * 256 + tid;     // 16384 elems
    const float* p = xyz2 + (size_t)t * 3;
    float x = p[0], y = p[1], z = p[2];
    xyz2p[t] = make_float4(x, y, z, x * x + y * y + z * z);
  }
}

// ---------------------------------------------- fused nn+interp+MLP -------
// 1024 blocks x 512 threads; block owns 64 points of batch b = bi&7 (XCD-local
// points2/xyz2p in that XCD's L2). Wave w = candidate chunk of 256.
__global__ __launch_bounds__(512, 6) void fp_fused_kernel(
    const float* __restrict__ xyz1, const float4* __restrict__ xyz2p,
    const float* __restrict__ points1, const float* __restrict__ points2,
    const bf16_t* __restrict__ W1T, const float* __restrict__ b1,
    const bf16_t* __restrict__ W2T, const float* __restrict__ b2,
    float* __restrict__ out) {
  // LDS map. Scan phase: sdv [0,8K), siv [8K,16K), cand stage [16K,48K).
  // Gather..L2 phases: Xs [64][384] bf16 swizzled (48KB) overlays all;
  // Y1 [64][256] overlays Xs after layer 1.
  __shared__ __align__(16) char smem[64 * 768];   // 49152 B

  int bi = blockIdx.x;
  int b = bi & 7;                  // batch -> XCD (round-robin)
  int base = (bi >> 3) * 64;       // tile within batch (0..127)
  int tid = threadIdx.x;
  int wave = __builtin_amdgcn_readfirstlane(tid >> 6);  // 0..7
  int lane = tid & 63;
  size_t bN = (size_t)b * N_ + base;

  float4* sdv = (float4*)smem;             // [8][64] biased top-3 dists
  int4*   siv = (int4*)(smem + 8192);      // [8][64] top-3 indices
  float4* cst = (float4*)(smem + 16384);   // [2048] staged xyz2p{x,y,z,|q|^2}

  float w0, w1, w2;                // blend weights (lane = point)
  int   i0, i1, i2;                // top-3 indices (lane = point)

  // ===== Stage xyz2p[b] -> LDS (32KB, coalesced 64B/thread) ===============
  {
    const float4* src = xyz2p + b * M_;
#pragma unroll
    for (int t = 0; t < 4; ++t)
      cst[tid + t * 512] = src[tid + t * 512];
  }
  __syncthreads();

  // ===== Phase S: three_nn, online-hierarchical, LDS-fed. =================
  // wave = chunk of 256 cands, lane = point; candidate addresses are
  // wave-uniform -> ds_read same-address broadcast (conflict-free).
  {
    const float* p1 = xyz1 + (bN + lane) * 3;
    float x = p1[0], y = p1[1], z = p1[2];
    float sq1 = x * x + y * y + z * z;
    float m2x = -2.0f * x, m2y = -2.0f * y, m2z = -2.0f * z;

    const float4* p2 = cst + (wave << 8);  // wave-uniform LDS base
    int jb = wave << 8;

    auto dist = [&](const float4& qv) {
      return fmaf(m2x, qv.x, fmaf(m2y, qv.y, fmaf(m2z, qv.z, qv.w)));
    };

    // top-3 group-mins (6 regs, no arrays)
    float t0 = 1e30f, t1 = 1e30f, t2 = 1e30f;
    int   g0 = 0, g1 = 0, g2 = 0;
    auto insG = [&](float d, int g) {       // branchless, strict <
      bool l0 = d < t0, l1 = d < t1, l2 = d < t2;
      float n0 = fminf(t0, d);
      float n1 = __builtin_amdgcn_fmed3f(d, t0, t1);
      float n2 = __builtin_amdgcn_fmed3f(d, t1, t2);
      int u1 = l0 ? g0 : g;
      int u2 = l1 ? g1 : g;
      g0 = l0 ? g : g0;
      g1 = l1 ? u1 : g1;
      g2 = l2 ? u2 : g2;
      t0 = n0; t1 = n1; t2 = n2;
    };

#pragma unroll 2
    for (int g = 0; g < 32; ++g) {
      const float4* pg = p2 + (g << 3);
      float4 c0 = pg[0], c1 = pg[1], c2 = pg[2], c3 = pg[3];
      float4 c4 = pg[4], c5 = pg[5], c6 = pg[6], c7 = pg[7];
      float d0 = dist(c0), d1 = dist(c1), d2 = dist(c2), d3 = dist(c3);
      float d4 = dist(c4), d5 = dist(c5), d6 = dist(c6), d7 = dist(c7);
      float gm = fminf(fminf(fminf(d0, d1), fminf(d2, d3)),
                       fminf(fminf(d4, d5), fminf(d6, d7)));
      insG(gm, g);
    }

    // sort winning groups ascending (ref tie-break = ascending-index scan)
    int ga = min(g0, min(g1, g2));
    int gc = max(g0, max(g1, g2));
    int gb = g0 + g1 + g2 - ga - gc;

    // ---- Phase 3: exact rescan of the 3 winning groups (24 cands) ----
    float s0 = 1e30f, s1 = 1e30f, s2 = 1e30f;
    int   a0 = 0, a1 = 0, a2 = 0;
    auto procIdx = [&](const float4& qv, int jj) {
      float d = dist(qv);
      bool l0 = d < s0, l1 = d < s1, l2 = d < s2;
      float n0v = fminf(s0, d);
      float n1v = __builtin_amdgcn_fmed3f(d, s0, s1);
      float n2v = __builtin_amdgcn_fmed3f(d, s1, s2);
      int u1 = l0 ? a0 : jj;               // carry into slot1
      int u2 = l1 ? a1 : jj;               // carry into slot2
      a0 = l0 ? jj : a0;
      a1 = l1 ? u1 : a1;
      a2 = l2 ? u2 : a2;
      s0 = n0v; s1 = n1v; s2 = n2v;
    };
    auto scanGroup = [&](int gg) {         // per-lane LDS addresses
      const float4* pg = p2 + (gg << 3);
      int jg = jb + (gg << 3);
#pragma unroll 1
      for (int h = 0; h < 2; ++h) {        // 4 float4 transients max
        float4 c0 = pg[h * 4 + 0], c1 = pg[h * 4 + 1];
        float4 c2 = pg[h * 4 + 2], c3 = pg[h * 4 + 3];
        procIdx(c0, jg + h * 4 + 0);
        procIdx(c1, jg + h * 4 + 1);
        procIdx(c2, jg + h * 4 + 2);
        procIdx(c3, jg + h * 4 + 3);
      }
    };
    scanGroup(ga); scanGroup(gb); scanGroup(gc);

    sdv[wave * 64 + lane] = make_float4(s0 + sq1, s1 + sq1, s2 + sq1, 0.0f);
    siv[wave * 64 + lane] = make_int4(a0, a1, a2, 0);
  }
  __syncthreads();

  // ===== Fold: every lane folds its point's 8 chunk-partials (redundant
  // across waves -> no serialization, results live in regs of lane=point). ===
  {
    float4 d0 = sdv[lane];  int4 x0 = siv[lane];
    float t0 = d0.x, t1 = d0.y, t2 = d0.z;
    int   a0 = x0.x, a1 = x0.y, a2 = x0.z;
    auto ins = [&](float d, int j) {
      if (d < t2) {
        if (d < t1) {
          t2 = t1; a2 = a1;
          if (d < t0) { t1 = t0; a1 = a0; t0 = d; a0 = j; }
          else        { t1 = d;  a1 = j; }
        } else { t2 = d; a2 = j; }
      }
    };
#pragma unroll
    for (int c = 1; c < 8; ++c) {
      float4 dd = sdv[c * 64 + lane];  int4 xx = siv[c * 64 + lane];
      ins(dd.x, xx.x); ins(dd.y, xx.y); ins(dd.z, xx.z);
    }
    float e0 = fmaxf(t0, 1e-10f), e1 = fmaxf(t1, 1e-10f), e2 = fmaxf(t2, 1e-10f);
    float r0 = 1.0f / e0, r1 = 1.0f / e1, r2 = 1.0f / e2;
    float rs = 1.0f / (r0 + r1 + r2);
    w0 = r0 * rs; w1 = r1 * rs; w2 = r2 * rs;
    i0 = a0; i1 = a1; i2 = a2;
  }
  __syncthreads();   // sd/si/cst region about to be overwritten by Xs

  // ===== Phase A: gather -> Xs[64][384] bf16 swizzled ======================
  // wave w fills rows w*8..w*8+7 (interp cols 0..255 + skip cols 256..383).
#pragma unroll 2
  for (int i = 0; i < 8; ++i) {
    int p = wave * 8 + i;
    int j0 = __shfl(i0, p), j1 = __shfl(i1, p), j2 = __shfl(i2, p);
    float u0 = __shfl(w0, p), u1 = __shfl(w1, p), u2 = __shfl(w2, p);
    const float* g0 = points2 + ((size_t)b * M_ + j0) * C2 + lane * 4;
    const float* g1 = points2 + ((size_t)b * M_ + j1) * C2 + lane * 4;
    const float* g2 = points2 + ((size_t)b * M_ + j2) * C2 + lane * 4;
    float4 a0 = *(const float4*)g0;
    float4 a1 = *(const float4*)g1;
    float4 a2 = *(const float4*)g2;
    bf16x4_t v;
    v[0] = (bf16_t)(u0 * a0.x + u1 * a1.x + u2 * a2.x);
    v[1] = (bf16_t)(u0 * a0.y + u1 * a1.y + u2 * a2.y);
    v[2] = (bf16_t)(u0 * a0.z + u1 * a1.z + u2 * a2.z);
    v[3] = (bf16_t)(u0 * a0.w + u1 * a1.w + u2 * a2.w);
    int off = p * 768 + ((lane * 8) ^ (i << 4));      // (p&7)==i
    *(bf16x4_t*)(smem + off) = v;
    const float* pp1 = points1 + (bN + p) * C1 + lane * 2;
    float2 s = *(const float2*)pp1;
    bf16x2_t v2; v2[0] = (bf16_t)s.x; v2[1] = (bf16_t)s.y;
    int off2 = p * 768 + ((512 + lane * 4) ^ (i << 4));
    *(bf16x2_t*)(smem + off2) = v2;
  }
  __syncthreads();

  int q = lane >> 4, r = lane & 15;
  int rs8 = (r & 7) << 4;            // row-swizzle XOR (rows r,16+r,32+r,48+r)

  // ---- Layer 1: [64 x 384] x [384 x 256] -> Y1, wave owns 32 cols
  floatx4_t acc[4][2] = {};
  int cw = wave * 32;
  const bf16_t* wq0 = W1T + (size_t)(cw +      r) * K1;
  const bf16_t* wq1 = W1T + (size_t)(cw + 16 + r) * K1;
  for (int kk = 0; kk < 12; ++kk) {
    int k0 = kk * 32 + q * 8;
    int co = (k0 << 1) ^ rs8;
    bf16x8_t a0 = *(const bf16x8_t*)(smem + (     r) * 768 + co);
    bf16x8_t a1 = *(const bf16x8_t*)(smem + (16 + r) * 768 + co);
    bf16x8_t a2 = *(const bf16x8_t*)(smem + (32 + r) * 768 + co);
    bf16x8_t a3 = *(const bf16x8_t*)(smem + (48 + r) * 768 + co);
    bf16x8_t bb0 = *(const bf16x8_t*)(wq0 + k0);
    bf16x8_t bb1 = *(const bf16x8_t*)(wq1 + k0);
    acc[0][0] = __builtin_amdgcn_mfma_f32_16x16x32_bf16(a0, bb0, acc[0][0], 0, 0, 0);
    acc[1][0] = __builtin_amdgcn_mfma_f32_16x16x32_bf16(a1, bb0, acc[1][0], 0, 0, 0);
    acc[2][0] = __builtin_amdgcn_mfma_f32_16x16x32_bf16(a2, bb0, acc[2][0], 0, 0, 0);
    acc[3][0] = __builtin_amdgcn_mfma_f32_16x16x32_bf16(a3, bb0, acc[3][0], 0, 0, 0);
    acc[0][1] = __builtin_amdgcn_mfma_f32_16x16x32_bf16(a0, bb1, acc[0][1], 0, 0, 0);
    acc[1][1] = __builtin_amdgcn_mfma_f32_16x16x32_bf16(a1, bb1, acc[1][1], 0, 0, 0);
    acc[2][1] = __builtin_amdgcn_mfma_f32_16x16x32_bf16(a2, bb1, acc[2][1], 0, 0, 0);
    acc[3][1] = __builtin_amdgcn_mfma_f32_16x16x32_bf16(a3, bb1, acc[3][1], 0, 0, 0);
  }
  __syncthreads();   // Xs dead only when ALL waves finished layer-1 LDS reads

  // bias + relu -> Y1 [64][256] bf16 (overlays Xs, 512B rows, same swizzle)
#pragma unroll
  for (int ct = 0; ct < 2; ++ct) {
    int nn = cw + ct * 16 + r;
    float bias = b1[nn];
#pragma unroll
    for (int mt = 0; mt < 4; ++mt) {
#pragma unroll
      for (int reg = 0; reg < 4; ++reg) {
        int m = mt * 16 + q * 4 + reg;
        int off = (m << 9) + ((nn << 1) ^ ((m & 7) << 4));
        *(bf16_t*)(smem + off) = (bf16_t)fmaxf(acc[mt][ct][reg] + bias, 0.0f);
      }
    }
  }
  __syncthreads();

  // ---- Layer 2: [64 x 256] x [256 x 128] -> out, wave owns 16 cols
  floatx4_t acc2[4] = {};
  const bf16_t* vq = W2T + (size_t)(wave * 16 + r) * N1;
  for (int kk = 0; kk < 8; ++kk) {
    int k0 = kk * 32 + q * 8;
    int co = (k0 << 1) ^ rs8;
    bf16x8_t a0 = *(const bf16x8_t*)(smem + ((     r) << 9) + co);
    bf16x8_t a1 = *(const bf16x8_t*)(smem + ((16 + r) << 9) + co);
    bf16x8_t a2 = *(const bf16x8_t*)(smem + ((32 + r) << 9) + co);
    bf16x8_t a3 = *(const bf16x8_t*)(smem + ((48 + r) << 9) + co);
    bf16x8_t bb = *(const bf16x8_t*)(vq + k0);
    acc2[0] = __builtin_amdgcn_mfma_f32_16x16x32_bf16(a0, bb, acc2[0], 0, 0, 0);
    acc2[1] = __builtin_amdgcn_mfma_f32_16x16x32_bf16(a1, bb, acc2[1], 0, 0, 0);
    acc2[2] = __builtin_amdgcn_mfma_f32_16x16x32_bf16(a2, bb, acc2[2], 0, 0, 0);
    acc2[3] = __builtin_amdgcn_mfma_f32_16x16x32_bf16(a3, bb, acc2[3], 0, 0, 0);
  }
  {
    int cc = wave * 16 + r;
    float bias = b2[cc];
#pragma unroll
    for (int mt = 0; mt < 4; ++mt) {
#pragma unroll
      for (int reg = 0; reg < 4; ++reg) {
        int m = mt * 16 + q * 4 + reg;
        out[(bN + m) * N2 + cc] = fmaxf(acc2[mt][reg] + bias, 0.0f);
      }
    }
  }
}

// ----------------------------------------------------------------- launch --
extern "C" void kernel_launch(void* const* d_in, const int* in_sizes, int n_in,
                              void* d_out, int out_size, void* d_ws, size_t ws_size,
                              hipStream_t stream) {
  (void)in_sizes; (void)n_in; (void)out_size; (void)ws_size;
  const float* xyz1    = (const float*)d_in[0];
  const float* xyz2    = (const float*)d_in[1];
  const float* points1 = (const float*)d_in[2];
  const float* points2 = (const float*)d_in[3];
  const float* W1      = (const float*)d_in[4];
  const float* b1      = (const float*)d_in[5];
  const float* W2      = (const float*)d_in[6];
  const float* b2      = (const float*)d_in[7];
  float* out = (float*)d_out;
  char* ws = (char*)d_ws;
  bf16_t* W1T   = (bf16_t*)(ws + WS_W1T);
  bf16_t* W2T   = (bf16_t*)(ws + WS_W2T);
  float4* xyz2p = (float4*)(ws + WS_XYZ2P);

  prep_kernel<<<576, 256, 0, stream>>>(W1, W2, xyz2, W1T, W2T, xyz2p);
  fp_fused_kernel<<<1024, 512, 0, stream>>>(xyz1, xyz2p, points1, points2,
                                            W1T, b1, W2T, b2, out);
}